// Round 4
// baseline (1601.047 us; speedup 1.0000x reference)
//
#include <hip/hip_runtime.h>

// LSTM: B=256, T=8192, I=5, H=16, fc -> 1.  One wave per batch element.
// Lane g owns gate g (q=g>>4: 0=i,1=f,2=g(tanh),3=o; j=g&15). h[j],c[j]
// replicated across the 4 16-lane rows.
// R4: h-dot via DPP row_ror fmac chains (no readlane), x repacked stride-8
// in LDS (b128+b32 per step), slot-alternating unroll-4 inner loop.

__device__ __forceinline__ void plswap32(float& a, float& b) {
#if __has_builtin(__builtin_amdgcn_permlane32_swap)
    auto r = __builtin_amdgcn_permlane32_swap(__float_as_uint(a),
                                              __float_as_uint(b), false, false);
    a = __uint_as_float(r[0]);
    b = __uint_as_float(r[1]);
#else
    unsigned ao, bo;
    asm("v_mov_b32 %0, %2\n\t"
        "v_mov_b32 %1, %3\n\t"
        "v_permlane32_swap_b32 %0, %1"
        : "=&v"(ao), "=&v"(bo)
        : "v"(__float_as_uint(a)), "v"(__float_as_uint(b)));
    a = __uint_as_float(ao);
    b = __uint_as_float(bo);
#endif
}

__device__ __forceinline__ void plswap16(float& a, float& b) {
#if __has_builtin(__builtin_amdgcn_permlane16_swap)
    auto r = __builtin_amdgcn_permlane16_swap(__float_as_uint(a),
                                              __float_as_uint(b), false, false);
    a = __uint_as_float(r[0]);
    b = __uint_as_float(r[1]);
#else
    unsigned ao, bo;
    asm("v_mov_b32 %0, %2\n\t"
        "v_mov_b32 %1, %3\n\t"
        "v_permlane16_swap_b32 %0, %1"
        : "=&v"(ao), "=&v"(bo)
        : "v"(__float_as_uint(a)), "v"(__float_as_uint(b)));
    a = __uint_as_float(ao);
    b = __uint_as_float(bo);
#endif
}

// h rotated by R within each 16-lane row (DPP row_ror, foldable into v_fmac).
template <int R>
__device__ __forceinline__ float hrot(float h) {
    if constexpr (R == 0) {
        return h;
    } else {
        return __uint_as_float((unsigned)__builtin_amdgcn_update_dpp(
            (int)__float_as_uint(h), (int)__float_as_uint(h),
            0x120 + R, 0xf, 0xf, false));
    }
}

__global__ __launch_bounds__(64, 1) void lstm_fused(
    const float* __restrict__ x,      // [B, T, 5]
    const float* __restrict__ W_ih,   // [64, 5]
    const float* __restrict__ W_hh,   // [64, 16]
    const float* __restrict__ b_ih,   // [64]
    const float* __restrict__ b_hh,   // [64]
    const float* __restrict__ fc_w,   // [1, 16]
    const float* __restrict__ fc_b,   // [1]
    float* __restrict__ out,          // [B, T]
    int T)
{
    const int b    = blockIdx.x;
    const int lane = threadIdx.x;     // 0..63
    const int jj   = lane & 15;
    const int q    = lane >> 4;
    const bool isg = (q == 2);

    // Pre-scale weights by -log2e (sigmoid) / -2log2e (tanh gate):
    // sigma(z) = 1/(1+exp2(z')) with z' already scaled.
    const float LOG2E  = 1.4426950408889634f;
    const float wscale = isg ? (-2.0f * LOG2E) : (-LOG2E);
    const float post_m = isg ?  2.0f : 1.0f;
    const float post_a = isg ? -1.0f : 0.0f;

    float wi[5];
#pragma unroll
    for (int i = 0; i < 5; ++i) wi[i] = W_ih[lane * 5 + i] * wscale;
    const float bias = (b_ih[lane] + b_hh[lane]) * wscale;

    // Self-calibrated rotation weights: whr[r] = W_hh[gate, src_lane_j(r)],
    // where src_lane_j(r) is whatever lane hrot<r> actually reads from.
    float whr[16];
    whr[0] = W_hh[lane * 16 + jj] * wscale;
#define CALIB(R)                                                              \
    {                                                                         \
        int p = __builtin_amdgcn_update_dpp(jj, jj, 0x120 + R, 0xf, 0xf, false); \
        whr[R] = W_hh[lane * 16 + p] * wscale;                                \
    }
    CALIB(1) CALIB(2) CALIB(3) CALIB(4) CALIB(5) CALIB(6) CALIB(7)
    CALIB(8) CALIB(9) CALIB(10) CALIB(11) CALIB(12) CALIB(13) CALIB(14) CALIB(15)
#undef CALIB

    float fw[16];                      // uniform -> SGPRs
#pragma unroll
    for (int k = 0; k < 16; ++k) fw[k] = fc_w[k];
    const float fcb = fc_b[0];

    __shared__ __align__(32) float ls_xp[1024];  // 2 halves x 64 rows x 8 (stride-8 pack)
    __shared__ float ls_h[64 * 17];              // stride 17: conflict-free

    const float* __restrict__ xb = x   + (size_t)b * T * 5;
    float*       __restrict__ yb = out + (size_t)b * T;
    const int NC = T >> 6;             // 64-step chunks

    // ---- Prologue: repack chunk 0 into LDS half 0; chunk 1 rows in rp. ----
    float rp[5];
    {
        const float* g0 = xb + lane * 5;
#pragma unroll
        for (int k = 0; k < 5; ++k) ls_xp[lane * 8 + k] = g0[k];
        if (NC > 1) {
            const float* g1 = xb + 320 + lane * 5;
#pragma unroll
            for (int k = 0; k < 5; ++k) rp[k] = g1[k];
        } else {
#pragma unroll
            for (int k = 0; k < 5; ++k) rp[k] = 0.0f;
        }
    }

    // Preload rows 0,1 of chunk 0 into the two slots.
    float4 sv0 = *(const float4*)&ls_xp[0];
    float  s40 = ls_xp[4];
    float4 sv1 = *(const float4*)&ls_xp[8];
    float  s41 = ls_xp[12];

    float c = 0.0f, h = 0.0f;

#define LSTM_STEP(SV, S4, TPE)                                                \
    do {                                                                      \
        const int tpv = (TPE);                                                \
        /* x-partial seeds (consume slot BEFORE reload) */                    \
        float a0 = fmaf(SV.x, wi[0], bias);                                   \
        float a1 = SV.y * wi[1];                                              \
        float a2 = SV.z * wi[2];                                              \
        float a3 = SV.w * wi[3];                                              \
        a0 = fmaf(S4, wi[4], a0);                                             \
        /* prefetch row tpv+2 straight into the slot (distance 2) */          \
        int w_ = base + (tpv + 2) * 8;                                        \
        w_ = (w_ >= 1024) ? (w_ - 1024) : w_;                                 \
        SV = *(const float4*)&ls_xp[w_];                                      \
        S4 = ls_xp[w_ + 4];                                                   \
        /* h-dot: 4 DPP-fmac chains of 4 */                                   \
        a0 = fmaf(h,         whr[0],  a0);                                    \
        a0 = fmaf(hrot<1>(h),  whr[1],  a0);                                  \
        a0 = fmaf(hrot<2>(h),  whr[2],  a0);                                  \
        a0 = fmaf(hrot<3>(h),  whr[3],  a0);                                  \
        a1 = fmaf(hrot<4>(h),  whr[4],  a1);                                  \
        a1 = fmaf(hrot<5>(h),  whr[5],  a1);                                  \
        a1 = fmaf(hrot<6>(h),  whr[6],  a1);                                  \
        a1 = fmaf(hrot<7>(h),  whr[7],  a1);                                  \
        a2 = fmaf(hrot<8>(h),  whr[8],  a2);                                  \
        a2 = fmaf(hrot<9>(h),  whr[9],  a2);                                  \
        a2 = fmaf(hrot<10>(h), whr[10], a2);                                  \
        a2 = fmaf(hrot<11>(h), whr[11], a2);                                  \
        a3 = fmaf(hrot<12>(h), whr[12], a3);                                  \
        a3 = fmaf(hrot<13>(h), whr[13], a3);                                  \
        a3 = fmaf(hrot<14>(h), whr[14], a3);                                  \
        a3 = fmaf(hrot<15>(h), whr[15], a3);                                  \
        const float pre = (a0 + a1) + (a2 + a3);                              \
        /* activation */                                                      \
        const float e_   = __builtin_amdgcn_exp2f(pre);                       \
        const float s_   = __builtin_amdgcn_rcpf(1.0f + e_);                  \
        const float act  = fmaf(post_m, s_, post_a);                          \
        /* gather i,f,g,o to all lanes */                                     \
        float A1 = act, B1 = act;                                             \
        plswap32(A1, B1);   /* A1=[i,f,i,f], B1=[g,o,g,o] */                  \
        float iv = A1, fv = A1;                                               \
        plswap16(iv, fv);                                                     \
        float gv = B1, ov = B1;                                               \
        plswap16(gv, ov);                                                     \
        /* state update */                                                    \
        c = fmaf(fv, c, iv * gv);                                             \
        const float e2 = __builtin_amdgcn_exp2f(c * -2.8853900817779268f);    \
        const float r2 = __builtin_amdgcn_rcpf(1.0f + e2);                    \
        h = ov * fmaf(2.0f, r2, -1.0f);                                       \
        ls_h[tpv * 17 + jj] = h;                                              \
    } while (0)

    for (int n = 0; n < NC; ++n) {
        const int base = (n & 1) * 512;

        // Stage chunk n+1 into the other half; issue loads for chunk n+2.
        if (n + 1 < NC) {
            const int dh = ((n + 1) & 1) * 512;
#pragma unroll
            for (int k = 0; k < 5; ++k) ls_xp[dh + lane * 8 + k] = rp[k];
            if (n + 2 < NC) {
                const float* g2 = xb + (size_t)(n + 2) * 320 + lane * 5;
#pragma unroll
                for (int k = 0; k < 5; ++k) rp[k] = g2[k];
            }
        }

        for (int tp = 0; tp < 64; tp += 4) {
            LSTM_STEP(sv0, s40, tp);
            LSTM_STEP(sv1, s41, tp + 1);
            LSTM_STEP(sv0, s40, tp + 2);
            LSTM_STEP(sv1, s41, tp + 3);
        }

        // Batched output projection: lane l handles step n*64+l.
        float y = fcb;
#pragma unroll
        for (int k = 0; k < 16; ++k) y = fmaf(ls_h[lane * 17 + k], fw[k], y);
        yb[(n << 6) + lane] = y;
    }
#undef LSTM_STEP
}

extern "C" void kernel_launch(void* const* d_in, const int* in_sizes, int n_in,
                              void* d_out, int out_size, void* d_ws, size_t ws_size,
                              hipStream_t stream) {
    const float* x    = (const float*)d_in[0];
    const float* W_ih = (const float*)d_in[1];
    const float* W_hh = (const float*)d_in[2];
    const float* b_ih = (const float*)d_in[3];
    const float* b_hh = (const float*)d_in[4];
    const float* fc_w = (const float*)d_in[5];
    const float* fc_b = (const float*)d_in[6];
    float* out = (float*)d_out;

    const int B = 256;
    const int T = out_size / B;   // 8192

    lstm_fused<<<dim3(B), dim3(64), 0, stream>>>(
        x, W_ih, W_hh, b_ih, b_hh, fc_w, fc_b, out, T);
}

// Round 5
// 1405.028 us; speedup vs baseline: 1.1395x; 1.1395x over previous
//
#include <hip/hip_runtime.h>

// LSTM: B=256, T=8192, I=5, H=16, fc -> 1.  One wave per batch element.
// Lane g owns gate g (q=g>>4: 0=i,1=f,2=g(tanh),3=o; j=g&15). h,c replicated
// across the 4 16-lane rows.
// R5: h-dot bulk via LDS broadcast (write h once, 3x uniform ds_read_b128
// consumed next step), head h[0..3] via readlane; x stride-8 packed in LDS
// (b128+b32 per step); 2-slot unrolled inner loop.
// R4 lesson: update_dpp ties old->dst => +30 instrs of movs; DPP dropped.

__device__ __forceinline__ float readlane_f(float v, int l) {
    return __int_as_float(__builtin_amdgcn_readlane(__float_as_int(v), l));
}

__device__ __forceinline__ void plswap32(float& a, float& b) {
#if __has_builtin(__builtin_amdgcn_permlane32_swap)
    auto r = __builtin_amdgcn_permlane32_swap(__float_as_uint(a),
                                              __float_as_uint(b), false, false);
    a = __uint_as_float(r[0]);
    b = __uint_as_float(r[1]);
#else
    unsigned ao, bo;
    asm("v_mov_b32 %0, %2\n\t"
        "v_mov_b32 %1, %3\n\t"
        "v_permlane32_swap_b32 %0, %1"
        : "=&v"(ao), "=&v"(bo)
        : "v"(__float_as_uint(a)), "v"(__float_as_uint(b)));
    a = __uint_as_float(ao);
    b = __uint_as_float(bo);
#endif
}

__device__ __forceinline__ void plswap16(float& a, float& b) {
#if __has_builtin(__builtin_amdgcn_permlane16_swap)
    auto r = __builtin_amdgcn_permlane16_swap(__float_as_uint(a),
                                              __float_as_uint(b), false, false);
    a = __uint_as_float(r[0]);
    b = __uint_as_float(r[1]);
#else
    unsigned ao, bo;
    asm("v_mov_b32 %0, %2\n\t"
        "v_mov_b32 %1, %3\n\t"
        "v_permlane16_swap_b32 %0, %1"
        : "=&v"(ao), "=&v"(bo)
        : "v"(__float_as_uint(a)), "v"(__float_as_uint(b)));
    a = __uint_as_float(ao);
    b = __uint_as_float(bo);
#endif
}

__global__ __launch_bounds__(64, 1) void lstm_fused(
    const float* __restrict__ x,      // [B, T, 5]
    const float* __restrict__ W_ih,   // [64, 5]
    const float* __restrict__ W_hh,   // [64, 16]
    const float* __restrict__ b_ih,   // [64]
    const float* __restrict__ b_hh,   // [64]
    const float* __restrict__ fc_w,   // [1, 16]
    const float* __restrict__ fc_b,   // [1]
    float* __restrict__ out,          // [B, T]
    int T)
{
    const int b    = blockIdx.x;
    const int lane = threadIdx.x;     // 0..63
    const int jj   = lane & 15;
    const int q    = lane >> 4;
    const bool isg = (q == 2);

    // Pre-scale weights by -log2e (sigmoid) / -2log2e (tanh gate):
    // activation = 1/(1+exp2(pre)) with pre already scaled.
    const float LOG2E  = 1.4426950408889634f;
    const float wscale = isg ? (-2.0f * LOG2E) : (-LOG2E);
    const float post_m = isg ?  2.0f : 1.0f;
    const float post_a = isg ? -1.0f : 0.0f;

    float wi[5];
#pragma unroll
    for (int i = 0; i < 5; ++i) wi[i] = W_ih[lane * 5 + i] * wscale;
    float wh[16];
#pragma unroll
    for (int k = 0; k < 16; ++k) wh[k] = W_hh[lane * 16 + k] * wscale;
    const float bias = (b_ih[lane] + b_hh[lane]) * wscale;

    float fw[16];                      // uniform -> SGPRs
#pragma unroll
    for (int k = 0; k < 16; ++k) fw[k] = fc_w[k];
    const float fcb = fc_b[0];

    __shared__ __align__(16) float ls_xp[1024];  // 2 halves x 64 rows x 8
    __shared__ __align__(16) float ls_hb[16];    // h broadcast buffer
    __shared__ float ls_h[64 * 17];              // per-step h for projection

    const float* __restrict__ xb = x   + (size_t)b * T * 5;
    float*       __restrict__ yb = out + (size_t)b * T;
    const int NC = T >> 6;             // 64-step chunks

    // ---- Prologue: repack chunk 0 into LDS half 0; chunk 1 rows in rp. ----
    float rp[5];
    {
        const float* g0 = xb + lane * 5;
#pragma unroll
        for (int k = 0; k < 5; ++k) ls_xp[lane * 8 + k] = g0[k];
        if (NC > 1) {
            const float* g1 = xb + 320 + lane * 5;
#pragma unroll
            for (int k = 0; k < 5; ++k) rp[k] = g1[k];
        } else {
#pragma unroll
            for (int k = 0; k < 5; ++k) rp[k] = 0.0f;
        }
    }

    // Slots: rows 0,1 of chunk 0 (uniform-address broadcast reads).
    float4 sv0 = *(const float4*)&ls_xp[0];
    float  s40 = ls_xp[4];
    float4 sv1 = *(const float4*)&ls_xp[8];
    float  s41 = ls_xp[12];

    float c = 0.0f, h = 0.0f;

    // h broadcast init (h = 0).
    ls_hb[jj] = 0.0f;
    float4 hb1 = *(const float4*)&ls_hb[4];
    float4 hb2 = *(const float4*)&ls_hb[8];
    float4 hb3 = *(const float4*)&ls_hb[12];

#define LSTM_STEP(SV, S4, TP)                                                 \
    {                                                                         \
        const int tpv = (TP);                                                 \
        /* x-partial seeds (consume slot BEFORE reload) */                    \
        float a0 = fmaf(SV.x, wi[0], bias);                                   \
        float a1 = SV.y * wi[1];                                              \
        float a2 = SV.z * wi[2];                                              \
        float a3 = SV.w * wi[3];                                              \
        a0 = fmaf(S4, wi[4], a0);                                             \
        /* prefetch x row tpv+2 into the slot (distance 2) */                 \
        int w_ = base + (tpv + 2) * 8;                                        \
        w_ = (w_ >= 1024) ? (w_ - 1024) : w_;                                 \
        SV = *(const float4*)&ls_xp[w_];                                      \
        S4 = ls_xp[w_ + 4];                                                   \
        /* h-dot: head via readlane (fast), bulk from LDS-broadcast regs */   \
        a0 = fmaf(readlane_f(h, 0), wh[0], a0);                               \
        a0 = fmaf(readlane_f(h, 1), wh[1], a0);                               \
        a0 = fmaf(readlane_f(h, 2), wh[2], a0);                               \
        a0 = fmaf(readlane_f(h, 3), wh[3], a0);                               \
        a1 = fmaf(hb1.x, wh[4],  a1);                                         \
        a1 = fmaf(hb1.y, wh[5],  a1);                                         \
        a1 = fmaf(hb1.z, wh[6],  a1);                                         \
        a1 = fmaf(hb1.w, wh[7],  a1);                                         \
        a2 = fmaf(hb2.x, wh[8],  a2);                                         \
        a2 = fmaf(hb2.y, wh[9],  a2);                                         \
        a2 = fmaf(hb2.z, wh[10], a2);                                         \
        a2 = fmaf(hb2.w, wh[11], a2);                                         \
        a3 = fmaf(hb3.x, wh[12], a3);                                         \
        a3 = fmaf(hb3.y, wh[13], a3);                                         \
        a3 = fmaf(hb3.z, wh[14], a3);                                         \
        a3 = fmaf(hb3.w, wh[15], a3);                                         \
        const float pre = (a0 + a1) + (a2 + a3);                              \
        /* activation: sigma or tanh (=2*sigma(2z)-1) via exp2+rcp */         \
        const float e_  = __builtin_amdgcn_exp2f(pre);                        \
        const float s_  = __builtin_amdgcn_rcpf(1.0f + e_);                   \
        const float act = fmaf(post_m, s_, post_a);                           \
        /* gather i,f,g,o to all lanes */                                     \
        float A1 = act, B1 = act;                                             \
        plswap32(A1, B1);      /* A1=[i,f,i,f], B1=[g,o,g,o] */               \
        float iv = A1, fv = A1;                                               \
        plswap16(iv, fv);                                                     \
        float gv = B1, ov = B1;                                               \
        plswap16(gv, ov);                                                     \
        /* state update */                                                    \
        c = fmaf(fv, c, iv * gv);                                             \
        const float e2 = __builtin_amdgcn_exp2f(c * -2.8853900817779268f);    \
        const float r2 = __builtin_amdgcn_rcpf(1.0f + e2);                    \
        h = ov * fmaf(2.0f, r2, -1.0f);                                       \
        /* broadcast h for next step: write once, read back 12 floats */      \
        ls_hb[jj] = h;                                                        \
        hb1 = *(const float4*)&ls_hb[4];                                      \
        hb2 = *(const float4*)&ls_hb[8];                                      \
        hb3 = *(const float4*)&ls_hb[12];                                     \
        /* stage h for the batched output projection */                       \
        ls_h[tpv * 17 + jj] = h;                                              \
    }

    for (int n = 0; n < NC; ++n) {
        const int base = (n & 1) * 512;

        // Stage chunk n+1 into the other half; issue loads for chunk n+2.
        if (n + 1 < NC) {
            const int dh = ((n + 1) & 1) * 512;
#pragma unroll
            for (int k = 0; k < 5; ++k) ls_xp[dh + lane * 8 + k] = rp[k];
            if (n + 2 < NC) {
                const float* g2 = xb + (size_t)(n + 2) * 320 + lane * 5;
#pragma unroll
                for (int k = 0; k < 5; ++k) rp[k] = g2[k];
            }
        }

        for (int tp = 0; tp < 64; tp += 2) {
            LSTM_STEP(sv0, s40, tp);
            LSTM_STEP(sv1, s41, tp + 1);
        }

        // Batched output projection: lane l handles step n*64+l.
        float y = fcb;
#pragma unroll
        for (int k = 0; k < 16; ++k) y = fmaf(ls_h[lane * 17 + k], fw[k], y);
        yb[(n << 6) + lane] = y;
    }
#undef LSTM_STEP
}

extern "C" void kernel_launch(void* const* d_in, const int* in_sizes, int n_in,
                              void* d_out, int out_size, void* d_ws, size_t ws_size,
                              hipStream_t stream) {
    const float* x    = (const float*)d_in[0];
    const float* W_ih = (const float*)d_in[1];
    const float* W_hh = (const float*)d_in[2];
    const float* b_ih = (const float*)d_in[3];
    const float* b_hh = (const float*)d_in[4];
    const float* fc_w = (const float*)d_in[5];
    const float* fc_b = (const float*)d_in[6];
    float* out = (float*)d_out;

    const int B = 256;
    const int T = out_size / B;   // 8192

    lstm_fused<<<dim3(B), dim3(64), 0, stream>>>(
        x, W_ih, W_hh, b_ih, b_hh, fc_w, fc_b, out, T);
}